// Round 2
// baseline (1661.409 us; speedup 1.0000x reference)
//
#include <hip/hip_runtime.h>

// out[n] = -0.1*(deg[n]*x[n] - Ax[n]) + 0.9*hyper_res[n]
// Folded per-edge:
//   adj edge (s,d):        out[d] += 0.1*(x[s] - x[d])
//   hyper edge (i0,i1,i2): p = x[i1]*x[i2]; out[ij] += 0.9*(p - x[ij]^2)
//
// Atomic-contention mitigation: NCOPIES private accumulators in d_ws,
// copy chosen by blockIdx % NCOPIES (matches round-robin XCD dispatch, so
// each copy stays hot in one XCD's L2). Final reduce sums the copies.

#define NCOPIES 8

__global__ __launch_bounds__(256) void zero_kernel(float4* __restrict__ p, long long n4) {
    long long tid    = (long long)blockIdx.x * blockDim.x + threadIdx.x;
    long long stride = (long long)gridDim.x * blockDim.x;
    for (long long i = tid; i < n4; i += stride)
        p[i] = make_float4(0.f, 0.f, 0.f, 0.f);
}

__global__ __launch_bounds__(256) void fused_scatter_kernel(
    const float* __restrict__ x,
    const int2*  __restrict__ adj,    // (n_adj, 2)
    const int*   __restrict__ hyper,  // (n_hyper, 3) flat
    float*       __restrict__ acc,    // ncopies * n_nodes floats
    int n_adj, int n_hyper, int n_nodes, int ncopies)
{
    float* __restrict__ my = acc + (long long)(blockIdx.x % ncopies) * n_nodes;

    const long long tid    = (long long)blockIdx.x * blockDim.x + threadIdx.x;
    const long long stride = (long long)gridDim.x * blockDim.x;

    // ---- adjacency edges: one atomic per edge ----
    for (long long i = tid; i < n_adj; i += stride) {
        int2 e = adj[i];                    // e.x = src, e.y = dst
        float v = 0.1f * (x[e.x] - x[e.y]);
        atomicAdd(&my[e.y], v);
    }

    // ---- hyper edges: three atomics per edge ----
    for (long long i = tid; i < n_hyper; i += stride) {
        int i0 = hyper[3 * i + 0];
        int i1 = hyper[3 * i + 1];
        int i2 = hyper[3 * i + 2];
        float x0 = x[i0], x1 = x[i1], x2 = x[i2];
        float p = x1 * x2;
        atomicAdd(&my[i0], 0.9f * (p - x0 * x0));
        atomicAdd(&my[i1], 0.9f * (p - x1 * x1));
        atomicAdd(&my[i2], 0.9f * (p - x2 * x2));
    }
}

__global__ __launch_bounds__(256) void reduce_kernel(
    const float4* __restrict__ ws, float4* __restrict__ out,
    int n4_per_copy, int ncopies)
{
    long long tid    = (long long)blockIdx.x * blockDim.x + threadIdx.x;
    long long stride = (long long)gridDim.x * blockDim.x;
    for (long long i = tid; i < n4_per_copy; i += stride) {
        float4 s = ws[i];
        for (int k = 1; k < ncopies; ++k) {
            float4 v = ws[(long long)k * n4_per_copy + i];
            s.x += v.x; s.y += v.y; s.z += v.z; s.w += v.w;
        }
        out[i] = s;
    }
}

extern "C" void kernel_launch(void* const* d_in, const int* in_sizes, int n_in,
                              void* d_out, int out_size, void* d_ws, size_t ws_size,
                              hipStream_t stream) {
    const float* x     = (const float*)d_in[0];
    // d_in[1] = t (unused scalar)
    const int*   hyper = (const int*)d_in[2];
    const int2*  adj   = (const int2*)d_in[3];
    float*       out   = (float*)d_out;

    const int n_nodes = in_sizes[0];              // 500000 (divisible by 4)
    const int n_hyper = in_sizes[2] / 3;
    const int n_adj   = in_sizes[3] / 2;

    const size_t need = (size_t)NCOPIES * n_nodes * sizeof(float);
    const int ncopies = (ws_size >= need) ? NCOPIES : 1;
    float* acc = (ncopies > 1) ? (float*)d_ws : out;

    const long long n4_total = (long long)ncopies * n_nodes / 4;

    // 1) zero accumulators (own kernel — hipMemsetAsync is not graph-capture safe)
    zero_kernel<<<1024, 256, 0, stream>>>((float4*)acc, n4_total);

    // 2) fused scatter with privatized accumulators
    fused_scatter_kernel<<<2048, 256, 0, stream>>>(x, adj, hyper, acc,
                                                   n_adj, n_hyper, n_nodes, ncopies);

    // 3) reduce copies into d_out (skip if we scattered directly into out)
    if (ncopies > 1) {
        reduce_kernel<<<512, 256, 0, stream>>>((const float4*)acc, (float4*)out,
                                               n_nodes / 4, ncopies);
    }
}

// Round 3
// 670.301 us; speedup vs baseline: 2.4786x; 2.4786x over previous
//
#include <hip/hip_runtime.h>

// out[n] = -0.1*(deg[n]*x[n] - Ax[n]) + 0.9*hyper_res[n]
// Folded per-edge updates (31M total):
//   adj edge (s,d):        out[d] += 0.1*(x[s] - x[d])
//   hyper edge (i0,i1,i2): p = x[i1]*x[i2]; out[ij] += 0.9*(p - x[ij]^2)
//
// R2 counters: 31M device-scope atomics -> 968 MB write-through (31B/atomic),
// bound at ~650 GB/s. Fix: bin updates into 62 node-buckets (records in d_ws),
// then accumulate per-bucket in LDS. Global atomics only for bucket cursors
// (~32K) and rare overflow.

#define W_BUCKET   8192            // nodes per bucket (power of 2)
#define W_SHIFT    13
#define NB_MAX     62              // ceil(500000/8192)
#define S_STAGE    128             // staged records per bucket per tile
#define A_THREADS  512
#define A_BLOCKS   512
#define ADJ_TILE   (A_THREADS * 4) // 2048 records/tile, mean 33/bucket
#define HYP_TILE   (A_THREADS * 2) // 1024 edges -> 3072 records, mean 50/bucket
#define B_PB       8               // phase-B blocks per bucket
#define CAP_BUCKET 540672          // 66*8192; mean fill 508K + 46σ slack

// ---------------- fallback path (R2's passing kernel) ----------------

__global__ __launch_bounds__(256) void zero_f4_kernel(float4* __restrict__ p, long long n4) {
    long long tid = (long long)blockIdx.x * blockDim.x + threadIdx.x;
    long long stride = (long long)gridDim.x * blockDim.x;
    for (long long i = tid; i < n4; i += stride) p[i] = make_float4(0.f, 0.f, 0.f, 0.f);
}

__global__ __launch_bounds__(256) void fused_scatter_kernel(
    const float* __restrict__ x, const int2* __restrict__ adj,
    const int* __restrict__ hyper, float* __restrict__ out,
    int n_adj, int n_hyper)
{
    const long long tid = (long long)blockIdx.x * blockDim.x + threadIdx.x;
    const long long stride = (long long)gridDim.x * blockDim.x;
    for (long long i = tid; i < n_adj; i += stride) {
        int2 e = adj[i];
        atomicAdd(&out[e.y], 0.1f * (x[e.x] - x[e.y]));
    }
    for (long long i = tid; i < n_hyper; i += stride) {
        int i0 = hyper[3*i], i1 = hyper[3*i+1], i2 = hyper[3*i+2];
        float x0 = x[i0], x1 = x[i1], x2 = x[i2];
        float p = x1 * x2;
        atomicAdd(&out[i0], 0.9f * (p - x0*x0));
        atomicAdd(&out[i1], 0.9f * (p - x1*x1));
        atomicAdd(&out[i2], 0.9f * (p - x2*x2));
    }
}

// ---------------- phase 0: zero cursors + direct accumulator ----------------

__global__ __launch_bounds__(256) void zero_int_kernel(int* __restrict__ p, int n) {
    int tid = blockIdx.x * blockDim.x + threadIdx.x;
    int stride = gridDim.x * blockDim.x;
    for (int i = tid; i < n; i += stride) p[i] = 0;
}

// ---------------- phase A: bin updates into per-bucket record arrays --------

__device__ __forceinline__ void append_rec(int dst, float v, int* cur, int2* stage,
                                           float* __restrict__ g_direct) {
    int b = dst >> W_SHIFT;
    int p = atomicAdd(&cur[b], 1);          // LDS atomic, returning
    if (p < S_STAGE) {
        stage[b * S_STAGE + p] = make_int2(dst & (W_BUCKET - 1), __float_as_int(v));
    } else {
        atomicAdd(&g_direct[dst], v);       // rare overflow: direct global
    }
}

__device__ __forceinline__ void flush_stage(int nb, int* cur, int* basev, int2* stage,
                                            int* __restrict__ g_cursor,
                                            int2* __restrict__ g_records,
                                            float* __restrict__ g_direct,
                                            int tid, int wave, int lane, int nwaves) {
    __syncthreads();
    // one wave issues ALL bucket-cursor atomics in a single instruction
    if (wave == 0 && lane < nb) {
        int c = min(cur[lane], S_STAGE);
        int base = 0;
        if (c > 0) base = atomicAdd(&g_cursor[lane], c);
        basev[lane] = base;
    }
    __syncthreads();
    // cooperative coalesced copy LDS -> global record regions
    for (int b = wave; b < nb; b += nwaves) {
        int c = min(cur[b], S_STAGE);
        long long base = basev[b];
        for (int r = lane; r < c; r += 64) {
            long long idx = base + r;
            int2 rec = stage[b * S_STAGE + r];
            if (idx < CAP_BUCKET) {
                g_records[(long long)b * CAP_BUCKET + idx] = rec;
            } else {  // capacity overflow: direct global
                atomicAdd(&g_direct[b * W_BUCKET + rec.x], __int_as_float(rec.y));
            }
        }
    }
    __syncthreads();
    for (int b = tid; b < nb; b += A_THREADS) cur[b] = 0;
    __syncthreads();
}

__global__ __launch_bounds__(A_THREADS) void binning_kernel(
    const float* __restrict__ x,
    const int2* __restrict__ adj, int n_adj,
    const int* __restrict__ hyper, int n_hyper,
    int* __restrict__ g_cursor,
    float* __restrict__ g_direct,
    int2* __restrict__ g_records,
    int nb)
{
    __shared__ int2 stage[NB_MAX * S_STAGE];   // 62 KB
    __shared__ int  cur[NB_MAX];
    __shared__ int  basev[NB_MAX];

    const int tid = threadIdx.x;
    const int wave = tid >> 6;
    const int lane = tid & 63;
    const int nwaves = A_THREADS >> 6;

    for (int b = tid; b < nb; b += A_THREADS) cur[b] = 0;
    __syncthreads();

    // ---- adjacency edges ----
    {
        long long per_blk = (n_adj + gridDim.x - 1) / gridDim.x;
        long long a0 = (long long)blockIdx.x * per_blk;
        long long a1 = min((long long)n_adj, a0 + per_blk);
        for (long long t0 = a0; t0 < a1; t0 += ADJ_TILE) {
            long long t1 = min(a1, t0 + ADJ_TILE);
            for (long long i = t0 + tid; i < t1; i += A_THREADS) {
                int2 e = adj[i];
                float v = 0.1f * (x[e.x] - x[e.y]);
                append_rec(e.y, v, cur, stage, g_direct);
            }
            flush_stage(nb, cur, basev, stage, g_cursor, g_records, g_direct,
                        tid, wave, lane, nwaves);
        }
    }

    // ---- hyper edges (3 records each) ----
    {
        long long per_blk = (n_hyper + gridDim.x - 1) / gridDim.x;
        long long h0 = (long long)blockIdx.x * per_blk;
        long long h1 = min((long long)n_hyper, h0 + per_blk);
        for (long long t0 = h0; t0 < h1; t0 += HYP_TILE) {
            long long t1 = min(h1, t0 + HYP_TILE);
            for (long long i = t0 + tid; i < t1; i += A_THREADS) {
                int i0 = hyper[3*i], i1 = hyper[3*i+1], i2 = hyper[3*i+2];
                float x0 = x[i0], x1 = x[i1], x2 = x[i2];
                float p = x1 * x2;
                append_rec(i0, 0.9f * (p - x0*x0), cur, stage, g_direct);
                append_rec(i1, 0.9f * (p - x1*x1), cur, stage, g_direct);
                append_rec(i2, 0.9f * (p - x2*x2), cur, stage, g_direct);
            }
            flush_stage(nb, cur, basev, stage, g_cursor, g_records, g_direct,
                        tid, wave, lane, nwaves);
        }
    }
}

// ---------------- phase B: per-bucket LDS accumulation ----------------

__global__ __launch_bounds__(512) void accumulate_kernel(
    const int2* __restrict__ g_records,
    const int*  __restrict__ g_cursor,
    float* __restrict__ partials)
{
    __shared__ float acc[W_BUCKET];            // 32 KB
    const int b = blockIdx.x / B_PB;
    const int j = blockIdx.x % B_PB;

    for (int i = threadIdx.x; i < W_BUCKET; i += blockDim.x) acc[i] = 0.f;
    __syncthreads();

    long long cnt = min(g_cursor[b], CAP_BUCKET);
    long long s = cnt * j / B_PB;
    long long e = cnt * (j + 1) / B_PB;
    const int2* rec = g_records + (long long)b * CAP_BUCKET;
    for (long long i = s + threadIdx.x; i < e; i += blockDim.x) {
        int2 r = rec[i];
        atomicAdd(&acc[r.x], __int_as_float(r.y));   // LDS atomic, no return
    }
    __syncthreads();

    float* p = partials + (long long)blockIdx.x * W_BUCKET;
    for (int i = threadIdx.x; i < W_BUCKET; i += blockDim.x) p[i] = acc[i];
}

// ---------------- phase C: reduce partials + direct into out ----------------

__global__ __launch_bounds__(256) void finalize_kernel(
    const float* __restrict__ partials,
    const float* __restrict__ g_direct,
    float* __restrict__ out, int n_nodes)
{
    int tid = blockIdx.x * blockDim.x + threadIdx.x;
    int stride = gridDim.x * blockDim.x;
    for (int n = tid; n < n_nodes; n += stride) {
        int b = n >> W_SHIFT, l = n & (W_BUCKET - 1);
        float s = g_direct[n];
        const float* p = partials + ((long long)b * B_PB) * W_BUCKET + l;
        #pragma unroll
        for (int j = 0; j < B_PB; ++j) s += p[(long long)j * W_BUCKET];
        out[n] = s;
    }
}

// ---------------- launcher ----------------

extern "C" void kernel_launch(void* const* d_in, const int* in_sizes, int n_in,
                              void* d_out, int out_size, void* d_ws, size_t ws_size,
                              hipStream_t stream) {
    const float* x     = (const float*)d_in[0];
    const int*   hyper = (const int*)d_in[2];
    const int2*  adj   = (const int2*)d_in[3];
    float*       out   = (float*)d_out;

    const int n_nodes = in_sizes[0];
    const int n_hyper = in_sizes[2] / 3;
    const int n_adj   = in_sizes[3] / 2;
    const int nb      = (n_nodes + W_BUCKET - 1) / W_BUCKET;

    // ws layout (byte offsets)
    const size_t off_cursor  = 0;                                  // 64 ints
    const size_t off_direct  = 256;                                // n_nodes f32
    size_t off_rec = off_direct + (size_t)n_nodes * 4;
    off_rec = (off_rec + 255) & ~(size_t)255;
    const size_t rec_bytes   = (size_t)NB_MAX * CAP_BUCKET * 8;
    size_t off_part = off_rec + rec_bytes;
    const size_t part_bytes  = (size_t)NB_MAX * B_PB * W_BUCKET * 4;
    const size_t need = off_part + part_bytes;

    if (nb <= NB_MAX && ws_size >= need) {
        int*   g_cursor  = (int*)  ((char*)d_ws + off_cursor);
        float* g_direct  = (float*)((char*)d_ws + off_direct);
        int2*  g_records = (int2*) ((char*)d_ws + off_rec);
        float* partials  = (float*)((char*)d_ws + off_part);

        // zero cursors + direct accumulator (contiguous prefix of ws)
        zero_int_kernel<<<256, 256, 0, stream>>>((int*)d_ws, (int)(off_rec / 4));

        binning_kernel<<<A_BLOCKS, A_THREADS, 0, stream>>>(
            x, adj, n_adj, hyper, n_hyper, g_cursor, g_direct, g_records, nb);

        accumulate_kernel<<<nb * B_PB, 512, 0, stream>>>(g_records, g_cursor, partials);

        finalize_kernel<<<1024, 256, 0, stream>>>(partials, g_direct, out, n_nodes);
    } else {
        // fallback: direct scatter into out (R2's passing path)
        zero_f4_kernel<<<512, 256, 0, stream>>>((float4*)out, n_nodes / 4);
        fused_scatter_kernel<<<2048, 256, 0, stream>>>(x, adj, hyper, out, n_adj, n_hyper);
    }
}

// Round 4
// 624.739 us; speedup vs baseline: 2.6594x; 1.0729x over previous
//
#include <hip/hip_runtime.h>
#include <hip/hip_fp16.h>

// out[n] = -0.1*(deg[n]*x[n] - Ax[n]) + 0.9*hyper_res[n]
// Folded per-edge updates (31M total):
//   adj edge (s,d):        out[d] += 0.1*(x[s] - x[d])
//   hyper edge (i0,i1,i2): p = x[i1]*x[i2]; out[ij] += 0.9*(p - x[ij]^2)
//
// R3 post-mortem: binning latency/barrier-bound (VALU 11%, HBM 13%, occ 42%),
// accumulate under-occupied. R4: 4-byte records (dst<<16 | fp16(v)) -> 32.5KB
// stage -> 4 blocks/CU, bigger tiles (8 flushes/block, 3 barriers each),
// accumulate at B_PB=16 with uint4 loads + non-returning LDS atomics.

#define W_BUCKET   8192
#define W_SHIFT    13
#define NB_MAX     62
#define S_STAGE    128             // staged records per bucket per tile
#define A_THREADS  512
#define A_BLOCKS   1024
#define ADJ_TILE   4096            // edges/tile  -> mean 66 rec/bucket
#define HYP_TILE   1536            // edges/tile  -> 4608 rec, mean 74/bucket
#define B_PB       16              // phase-B blocks per bucket
#define CAP_BUCKET 540672          // 66*8192; mean fill 500K + slack

// ---------------- fallback path ----------------

__global__ __launch_bounds__(256) void zero_f4_kernel(float4* __restrict__ p, long long n4) {
    long long tid = (long long)blockIdx.x * blockDim.x + threadIdx.x;
    long long stride = (long long)gridDim.x * blockDim.x;
    for (long long i = tid; i < n4; i += stride) p[i] = make_float4(0.f, 0.f, 0.f, 0.f);
}

__global__ __launch_bounds__(256) void fused_scatter_kernel(
    const float* __restrict__ x, const int2* __restrict__ adj,
    const int* __restrict__ hyper, float* __restrict__ out,
    int n_adj, int n_hyper)
{
    const long long tid = (long long)blockIdx.x * blockDim.x + threadIdx.x;
    const long long stride = (long long)gridDim.x * blockDim.x;
    for (long long i = tid; i < n_adj; i += stride) {
        int2 e = adj[i];
        atomicAdd(&out[e.y], 0.1f * (x[e.x] - x[e.y]));
    }
    for (long long i = tid; i < n_hyper; i += stride) {
        int i0 = hyper[3*i], i1 = hyper[3*i+1], i2 = hyper[3*i+2];
        float x0 = x[i0], x1 = x[i1], x2 = x[i2];
        float p = x1 * x2;
        atomicAdd(&out[i0], 0.9f * (p - x0*x0));
        atomicAdd(&out[i1], 0.9f * (p - x1*x1));
        atomicAdd(&out[i2], 0.9f * (p - x2*x2));
    }
}

// ---------------- phase 0 ----------------

__global__ __launch_bounds__(256) void zero_int_kernel(int* __restrict__ p, int n) {
    int tid = blockIdx.x * blockDim.x + threadIdx.x;
    int stride = gridDim.x * blockDim.x;
    for (int i = tid; i < n; i += stride) p[i] = 0;
}

// ---------------- phase A: bin updates into per-bucket record arrays --------

__device__ __forceinline__ void append_rec(int dst, float v, int* cur,
                                           unsigned int* stage,
                                           float* __restrict__ g_direct) {
    int b = dst >> W_SHIFT;
    int p = atomicAdd(&cur[b], 1);          // LDS atomic, returning
    if (p < S_STAGE) {
        unsigned int bits = (unsigned int)__half_as_ushort(__float2half(v));
        stage[b * S_STAGE + p] = ((unsigned int)(dst & (W_BUCKET - 1)) << 16) | bits;
    } else {
        atomicAdd(&g_direct[dst], v);       // rare overflow: full-precision direct
    }
}

__device__ __forceinline__ void flush_stage(int nb, int* cur, int* basev, int* cnts,
                                            unsigned int* stage,
                                            int* __restrict__ g_cursor,
                                            unsigned int* __restrict__ g_records,
                                            float* __restrict__ g_direct,
                                            int wave, int lane, int nwaves) {
    __syncthreads();                          // appends of this tile done
    if (wave == 0 && lane < nb) {
        int c = min(cur[lane], S_STAGE);
        cur[lane] = 0;                        // reset folded in (appends resume after B2)
        int base = 0;
        if (c > 0) base = atomicAdd(&g_cursor[lane], c);
        basev[lane] = base;
        cnts[lane]  = c;
    }
    __syncthreads();                          // basev/cnts ready, cur reset visible
    for (int b = wave; b < nb; b += nwaves) {
        int c = cnts[b];
        long long base = basev[b];
        for (int r = lane; r < c; r += 64) {
            long long idx = base + r;
            unsigned int rec = stage[b * S_STAGE + r];
            if (idx < CAP_BUCKET) {
                g_records[(long long)b * CAP_BUCKET + idx] = rec;
            } else {  // capacity overflow: direct global (decode fp16)
                float v = __half2float(__ushort_as_half((unsigned short)(rec & 0xffffu)));
                atomicAdd(&g_direct[b * W_BUCKET + (int)(rec >> 16)], v);
            }
        }
    }
    __syncthreads();                          // stage free for next tile
}

__global__ __launch_bounds__(A_THREADS) void binning_kernel(
    const float* __restrict__ x,
    const int2* __restrict__ adj, int n_adj,
    const int* __restrict__ hyper, int n_hyper,
    int* __restrict__ g_cursor,
    float* __restrict__ g_direct,
    unsigned int* __restrict__ g_records,
    int nb)
{
    __shared__ unsigned int stage[NB_MAX * S_STAGE];   // 31.75 KB
    __shared__ int cur[NB_MAX];
    __shared__ int basev[NB_MAX];
    __shared__ int cnts[NB_MAX];

    const int tid = threadIdx.x;
    const int wave = tid >> 6;
    const int lane = tid & 63;
    const int nwaves = A_THREADS >> 6;

    for (int b = tid; b < nb; b += A_THREADS) cur[b] = 0;
    __syncthreads();

    // ---- adjacency edges ----
    {
        long long per_blk = (n_adj + gridDim.x - 1) / gridDim.x;
        long long a0 = (long long)blockIdx.x * per_blk;
        long long a1 = min((long long)n_adj, a0 + per_blk);
        for (long long t0 = a0; t0 < a1; t0 += ADJ_TILE) {
            long long t1 = min(a1, t0 + ADJ_TILE);
            for (long long i = t0 + tid; i < t1; i += A_THREADS) {
                int2 e = adj[i];
                float v = 0.1f * (x[e.x] - x[e.y]);
                append_rec(e.y, v, cur, stage, g_direct);
            }
            flush_stage(nb, cur, basev, cnts, stage, g_cursor, g_records, g_direct,
                        wave, lane, nwaves);
        }
    }

    // ---- hyper edges (3 records each) ----
    {
        long long per_blk = (n_hyper + gridDim.x - 1) / gridDim.x;
        long long h0 = (long long)blockIdx.x * per_blk;
        long long h1 = min((long long)n_hyper, h0 + per_blk);
        for (long long t0 = h0; t0 < h1; t0 += HYP_TILE) {
            long long t1 = min(h1, t0 + HYP_TILE);
            for (long long i = t0 + tid; i < t1; i += A_THREADS) {
                int i0 = hyper[3*i], i1 = hyper[3*i+1], i2 = hyper[3*i+2];
                float x0 = x[i0], x1 = x[i1], x2 = x[i2];
                float p = x1 * x2;
                append_rec(i0, 0.9f * (p - x0*x0), cur, stage, g_direct);
                append_rec(i1, 0.9f * (p - x1*x1), cur, stage, g_direct);
                append_rec(i2, 0.9f * (p - x2*x2), cur, stage, g_direct);
            }
            flush_stage(nb, cur, basev, cnts, stage, g_cursor, g_records, g_direct,
                        wave, lane, nwaves);
        }
    }
}

// ---------------- phase B: per-bucket LDS accumulation ----------------

__device__ __forceinline__ void acc_one(float* acc, unsigned int rec) {
    float v = __half2float(__ushort_as_half((unsigned short)(rec & 0xffffu)));
    atomicAdd(&acc[rec >> 16], v);            // LDS atomic, no return
}

__global__ __launch_bounds__(512) void accumulate_kernel(
    const unsigned int* __restrict__ g_records,
    const int*  __restrict__ g_cursor,
    float* __restrict__ partials)
{
    __shared__ float acc[W_BUCKET];            // 32 KB
    const int b = blockIdx.x / B_PB;
    const int j = blockIdx.x % B_PB;

    for (int i = threadIdx.x; i < W_BUCKET; i += blockDim.x) acc[i] = 0.f;
    __syncthreads();

    long long cnt = min(g_cursor[b], CAP_BUCKET);
    long long g4  = (cnt + 3) >> 2;            // number of 4-record groups
    long long s4  = g4 * j / B_PB;
    long long e4  = g4 * (j + 1) / B_PB;
    const uint4* rec4 = (const uint4*)(g_records + (long long)b * CAP_BUCKET);

    for (long long i4 = s4 + threadIdx.x; i4 < e4; i4 += blockDim.x) {
        uint4 r = rec4[i4];
        long long base = i4 << 2;
        if (base + 3 < cnt) {
            acc_one(acc, r.x); acc_one(acc, r.y);
            acc_one(acc, r.z); acc_one(acc, r.w);
        } else {
            if (base + 0 < cnt) acc_one(acc, r.x);
            if (base + 1 < cnt) acc_one(acc, r.y);
            if (base + 2 < cnt) acc_one(acc, r.z);
            if (base + 3 < cnt) acc_one(acc, r.w);
        }
    }
    __syncthreads();

    float* p = partials + (long long)blockIdx.x * W_BUCKET;
    for (int i = threadIdx.x; i < W_BUCKET; i += blockDim.x) p[i] = acc[i];
}

// ---------------- phase C: reduce partials + direct into out ----------------

__global__ __launch_bounds__(256) void finalize_kernel(
    const float* __restrict__ partials,
    const float* __restrict__ g_direct,
    float* __restrict__ out, int n_nodes)
{
    int tid = blockIdx.x * blockDim.x + threadIdx.x;
    int stride = gridDim.x * blockDim.x;
    for (int n = tid; n < n_nodes; n += stride) {
        int b = n >> W_SHIFT, l = n & (W_BUCKET - 1);
        float s = g_direct[n];
        const float* p = partials + ((long long)b * B_PB) * W_BUCKET + l;
        #pragma unroll
        for (int j = 0; j < B_PB; ++j) s += p[(long long)j * W_BUCKET];
        out[n] = s;
    }
}

// ---------------- launcher ----------------

extern "C" void kernel_launch(void* const* d_in, const int* in_sizes, int n_in,
                              void* d_out, int out_size, void* d_ws, size_t ws_size,
                              hipStream_t stream) {
    const float* x     = (const float*)d_in[0];
    const int*   hyper = (const int*)d_in[2];
    const int2*  adj   = (const int2*)d_in[3];
    float*       out   = (float*)d_out;

    const int n_nodes = in_sizes[0];
    const int n_hyper = in_sizes[2] / 3;
    const int n_adj   = in_sizes[3] / 2;
    const int nb      = (n_nodes + W_BUCKET - 1) / W_BUCKET;

    // ws layout (byte offsets)
    const size_t off_cursor = 0;                                   // 64 ints
    const size_t off_direct = 256;                                 // n_nodes f32
    size_t off_rec = off_direct + (size_t)n_nodes * 4;
    off_rec = (off_rec + 255) & ~(size_t)255;
    const size_t rec_bytes  = (size_t)NB_MAX * CAP_BUCKET * 4;     // 4B records
    size_t off_part = off_rec + rec_bytes;
    off_part = (off_part + 255) & ~(size_t)255;
    const size_t part_bytes = (size_t)NB_MAX * B_PB * W_BUCKET * 4;
    const size_t need = off_part + part_bytes;

    if (nb <= NB_MAX && ws_size >= need) {
        int*          g_cursor  = (int*)          ((char*)d_ws + off_cursor);
        float*        g_direct  = (float*)        ((char*)d_ws + off_direct);
        unsigned int* g_records = (unsigned int*) ((char*)d_ws + off_rec);
        float*        partials  = (float*)        ((char*)d_ws + off_part);

        // zero cursors + direct accumulator (contiguous prefix of ws)
        zero_int_kernel<<<256, 256, 0, stream>>>((int*)d_ws, (int)(off_rec / 4));

        binning_kernel<<<A_BLOCKS, A_THREADS, 0, stream>>>(
            x, adj, n_adj, hyper, n_hyper, g_cursor, g_direct, g_records, nb);

        accumulate_kernel<<<nb * B_PB, 512, 0, stream>>>(g_records, g_cursor, partials);

        finalize_kernel<<<1024, 256, 0, stream>>>(partials, g_direct, out, n_nodes);
    } else {
        zero_f4_kernel<<<512, 256, 0, stream>>>((float4*)out, n_nodes / 4);
        fused_scatter_kernel<<<2048, 256, 0, stream>>>(x, adj, hyper, out, n_adj, n_hyper);
    }
}